// Round 1
// baseline (1146.107 us; speedup 1.0000x reference)
//
#include <hip/hip_runtime.h>

// ---- workspace layout (bytes) ----
#define HM_OFF   0u
#define ACT1_OFF 4718592u                     // hm: 256*96*96*2
#define ACT2_OFF (ACT1_OFF + 75497472u)       // act1: 256*64*48*48*2
#define ACT3_OFF (ACT2_OFF + 37748736u)       // act2: 256*128*24*24*2
#define W2A_OFF  (ACT3_OFF + 75497472u)       // act3: 256*64*48*48*2
#define W3A_OFF  (W2A_OFF + 262144u)          // w2a: 128*1024*2

using short8  = __attribute__((ext_vector_type(8))) short;
using floatx4 = __attribute__((ext_vector_type(4))) float;

static __device__ __forceinline__ float bf2f(unsigned short u) {
  union { unsigned int i; float f; } v; v.i = ((unsigned int)u) << 16; return v.f;
}
static __device__ __forceinline__ unsigned short f2bf(float f) {
  union { float f; unsigned int i; } v; v.f = f;
  unsigned int x = v.i;
  return (unsigned short)((x + 0x7FFFu + ((x >> 16) & 1u)) >> 16);  // RNE
}
static __device__ __forceinline__ uint4 pack8(const unsigned short* v) {
  uint4 p;
  p.x = (unsigned)v[0] | ((unsigned)v[1] << 16);
  p.y = (unsigned)v[2] | ((unsigned)v[3] << 16);
  p.z = (unsigned)v[4] | ((unsigned)v[5] << 16);
  p.w = (unsigned)v[6] | ((unsigned)v[7] << 16);
  return p;
}

// ============ prep: heatmap build + weight casts ============
// blocks 0..255: heatmap per frame; 256..319: w2->bf16; 320..383: w3 parity matrices
__global__ __launch_bounds__(256) void prep_kernel(
    const float* __restrict__ lm, const float* __restrict__ w2,
    const float* __restrict__ w3,
    unsigned short* __restrict__ hm, unsigned short* __restrict__ w2a,
    unsigned short* __restrict__ w3a) {
  int bid = blockIdx.x, tid = threadIdx.x;
  if (bid < 256) {
    unsigned int* hm32 = (unsigned int*)(hm + bid * 9216);
    for (int i = tid; i < 4608; i += 256) hm32[i] = 0u;
    __syncthreads();
    if (tid < 68) {
      float x = lm[bid * 136 + tid * 2 + 0] * 95.0f;
      float y = lm[bid * 136 + tid * 2 + 1] * 95.0f;
      int ix = (int)x, iy = (int)y;  // trunc toward zero, matches .astype(int32) for coords >= 0
      if (ix >= 0 && ix < 96 && iy >= 0 && iy < 96)
        hm[bid * 9216 + iy * 96 + ix] = 0x3F80;  // bf16 1.0
    }
  } else if (bid < 320) {
    int e = (bid - 256) * 2048 + tid * 8;  // w2 flat [128][1024] == A row-major
    float4 f0 = *(const float4*)(w2 + e);
    float4 f1 = *(const float4*)(w2 + e + 4);
    unsigned short v[8] = { f2bf(f0.x), f2bf(f0.y), f2bf(f0.z), f2bf(f0.w),
                            f2bf(f1.x), f2bf(f1.y), f2bf(f1.z), f2bf(f1.w) };
    *(uint4*)(w2a + e) = pack8(v);
  } else {
    int e = (bid - 320) * 2048 + tid * 8;  // w3a [cls][oc64][k512], k = ic*4 + a*2 + b
    unsigned short v[8];
#pragma unroll
    for (int j = 0; j < 8; j++) {
      int k = e + j;
      int c = k >> 15, rem = k & 32767;
      int oc = rem >> 9, kk = rem & 511;
      int ic = kk >> 2, a = (kk >> 1) & 1, b = kk & 1;
      int r = c >> 1, s = c & 1;
      int kh = 2 * a + 1 - r, kw = 2 * b + 1 - s;
      v[j] = f2bf(w3[((ic * 64 + oc) * 4 + kh) * 4 + kw]);
    }
    *(uint4*)(w3a + e) = pack8(v);
  }
}

// ============ conv1: [BT,4,96,96] -> relu -> act1 bf16 [BT,64,48,48] ============
// thread per output pixel, all 64 oc; weights via wave-uniform s_loads
__global__ __launch_bounds__(256) void conv1_kernel(
    const float* __restrict__ ident, const unsigned short* __restrict__ hm,
    const float* __restrict__ w1, const float* __restrict__ b1,
    unsigned short* __restrict__ act1) {
  int bt = blockIdx.y;
  int p = blockIdx.x * 256 + threadIdx.x;  // 0..2303
  int oh = p / 48, ow = p % 48;
  int b = bt >> 5;
  float in_reg[64];
#pragma unroll
  for (int ic = 0; ic < 3; ic++) {
    const float* src = ident + (b * 3 + ic) * 9216;
#pragma unroll
    for (int kh = 0; kh < 4; kh++) {
      int ih = 2 * oh + kh - 1;
#pragma unroll
      for (int kw = 0; kw < 4; kw++) {
        int iw = 2 * ow + kw - 1;
        bool ok = (ih >= 0) && (ih < 96) && (iw >= 0) && (iw < 96);
        in_reg[ic * 16 + kh * 4 + kw] = ok ? src[ih * 96 + iw] : 0.0f;
      }
    }
  }
  {
    const unsigned short* hsrc = hm + bt * 9216;
#pragma unroll
    for (int kh = 0; kh < 4; kh++) {
      int ih = 2 * oh + kh - 1;
#pragma unroll
      for (int kw = 0; kw < 4; kw++) {
        int iw = 2 * ow + kw - 1;
        bool ok = (ih >= 0) && (ih < 96) && (iw >= 0) && (iw < 96);
        in_reg[48 + kh * 4 + kw] = ok ? bf2f(hsrc[ih * 96 + iw]) : 0.0f;
      }
    }
  }
  unsigned short* dst = act1 + bt * 64 * 2304 + p;
#pragma unroll 1
  for (int oc = 0; oc < 64; oc++) {
    float a0 = 0.f, a1 = 0.f, a2 = 0.f, a3 = 0.f;
    const float* wrow = w1 + oc * 64;  // uniform -> s_load
#pragma unroll
    for (int t = 0; t < 64; t += 4) {
      a0 += in_reg[t + 0] * wrow[t + 0];
      a1 += in_reg[t + 1] * wrow[t + 1];
      a2 += in_reg[t + 2] * wrow[t + 2];
      a3 += in_reg[t + 3] * wrow[t + 3];
    }
    float acc = b1[oc] + ((a0 + a1) + (a2 + a3));
    dst[oc * 2304] = f2bf(fmaxf(acc, 0.0f));
  }
}

// ============ conv2 (MFMA): act1 -> relu -> act2 bf16 [BT,128,24,24] ============
// GEMM per frame: C[128][576] = w2a[128][1024] * im2col[1024][576]; tile 128x64, KB=32
__global__ __launch_bounds__(256) void conv2_kernel(
    const unsigned short* __restrict__ act1, const unsigned short* __restrict__ w2a,
    const float* __restrict__ b2, unsigned short* __restrict__ act2) {
  __shared__ unsigned short Alds[128 * 32];  // [m][k] k-contig
  __shared__ unsigned short Blds[64 * 32];   // [n][k] k-contig
  int tid = threadIdx.x;
  int nb = blockIdx.x, bt = blockIdx.y;
  int wave = tid >> 6, lane = tid & 63, quad = lane >> 4, l16 = lane & 15;
  int nB = tid & 63, kg = tid >> 6;
  int pB = nb * 64 + nB;
  int ohB = pB / 24, owB = pB % 24;
  const unsigned short* a1 = act1 + bt * 64 * 2304;

  floatx4 acc[2][4];
#pragma unroll
  for (int i = 0; i < 2; i++)
#pragma unroll
    for (int j = 0; j < 4; j++) acc[i][j] = (floatx4){0.f, 0.f, 0.f, 0.f};

  for (int kk = 0; kk < 32; kk++) {
    // A tile: 128x32 = 4096 bf16, 2 x uint4 per thread
    uint4 av[2];
#pragma unroll
    for (int v = 0; v < 2; v++) {
      int e = v * 2048 + tid * 8;
      int row = e >> 5, kin = e & 31;
      av[v] = *(const uint4*)(w2a + row * 1024 + kk * 32 + kin);
    }
    // B gather: 8 bf16 per thread (one ic, 2 kh, 4 kw)
    unsigned short vals[8];
    int k0 = kk * 32 + kg * 8;
    int ic = k0 >> 4;
    int rr = k0 & 15;
#pragma unroll
    for (int j = 0; j < 8; j++) {
      int r2 = rr + j;
      int kh = r2 >> 2, kw = r2 & 3;
      int ih = 2 * ohB + kh - 1, iw = 2 * owB + kw - 1;
      bool ok = (ih >= 0) && (ih < 48) && (iw >= 0) && (iw < 48);
      vals[j] = ok ? a1[ic * 2304 + ih * 48 + iw] : (unsigned short)0;
    }
    __syncthreads();  // prior iteration's frag reads done
#pragma unroll
    for (int v = 0; v < 2; v++) {
      int e = v * 2048 + tid * 8;
      *(uint4*)(Alds + e) = av[v];
    }
    *(uint4*)(Blds + nB * 32 + kg * 8) = pack8(vals);
    __syncthreads();
    short8 bfrag[4];
#pragma unroll
    for (int nf = 0; nf < 4; nf++)
      bfrag[nf] = *(const short8*)(Blds + (nf * 16 + l16) * 32 + quad * 8);
#pragma unroll
    for (int mf = 0; mf < 2; mf++) {
      int m = wave * 32 + mf * 16 + l16;
      short8 afrag = *(const short8*)(Alds + m * 32 + quad * 8);
#pragma unroll
      for (int nf = 0; nf < 4; nf++)
        acc[mf][nf] = __builtin_amdgcn_mfma_f32_16x16x32_bf16(afrag, bfrag[nf], acc[mf][nf], 0, 0, 0);
    }
  }
  // epilogue: row = quad*4+reg, col = l16
#pragma unroll
  for (int mf = 0; mf < 2; mf++) {
#pragma unroll
    for (int nf = 0; nf < 4; nf++) {
      int p = nb * 64 + nf * 16 + l16;
#pragma unroll
      for (int reg = 0; reg < 4; reg++) {
        int oc = wave * 32 + mf * 16 + quad * 4 + reg;
        float v = acc[mf][nf][reg] + b2[oc];
        act2[(bt * 128 + oc) * 576 + p] = f2bf(fmaxf(v, 0.f));
      }
    }
  }
}

// ============ deconv3 (MFMA): act2 -> relu -> act3 bf16 [BT,64,48,48] ============
// per (frame, parity class): C[64][576] = w3a_c[64][512] * B_c[512][576]
__global__ __launch_bounds__(256) void deconv3_kernel(
    const unsigned short* __restrict__ act2, const unsigned short* __restrict__ w3a,
    const float* __restrict__ b3, unsigned short* __restrict__ act3) {
  __shared__ unsigned short Alds[64 * 32];
  __shared__ unsigned short Blds[64 * 32];
  int tid = threadIdx.x;
  int nb = blockIdx.x, cls = blockIdx.y, bt = blockIdx.z;
  int r = cls >> 1, s = cls & 1;
  int wave = tid >> 6, lane = tid & 63, quad = lane >> 4, l16 = lane & 15;
  int nB = tid & 63, kg = tid >> 6;
  int pB = nb * 64 + nB;
  int iB = pB / 24, jB = pB % 24;
  const unsigned short* a2 = act2 + bt * 128 * 576;
  const unsigned short* Ag = w3a + cls * 64 * 512;

  floatx4 acc[4];
#pragma unroll
  for (int j = 0; j < 4; j++) acc[j] = (floatx4){0.f, 0.f, 0.f, 0.f};

  for (int kk = 0; kk < 16; kk++) {
    int e = tid * 8, row = e >> 5, kin = e & 31;
    uint4 av = *(const uint4*)(Ag + row * 512 + kk * 32 + kin);
    unsigned short vals[8];
    int k0 = kk * 32 + kg * 8;
#pragma unroll
    for (int j = 0; j < 8; j++) {
      int k = k0 + j;
      int ic = k >> 2, a = (k >> 1) & 1, bb = k & 1;
      int ih = iB + r - a, iw = jB + s - bb;
      bool ok = (ih >= 0) && (ih < 24) && (iw >= 0) && (iw < 24);
      vals[j] = ok ? a2[ic * 576 + ih * 24 + iw] : (unsigned short)0;
    }
    __syncthreads();
    *(uint4*)(Alds + e) = av;
    *(uint4*)(Blds + nB * 32 + kg * 8) = pack8(vals);
    __syncthreads();
    short8 afrag = *(const short8*)(Alds + (wave * 16 + l16) * 32 + quad * 8);
#pragma unroll
    for (int nf = 0; nf < 4; nf++) {
      short8 bfrag = *(const short8*)(Blds + (nf * 16 + l16) * 32 + quad * 8);
      acc[nf] = __builtin_amdgcn_mfma_f32_16x16x32_bf16(afrag, bfrag, acc[nf], 0, 0, 0);
    }
  }
#pragma unroll
  for (int nf = 0; nf < 4; nf++) {
    int p = nb * 64 + nf * 16 + l16;
    int i = p / 24, j = p % 24;
    int oh = 2 * i + r, ow = 2 * j + s;
#pragma unroll
    for (int reg = 0; reg < 4; reg++) {
      int oc = wave * 16 + quad * 4 + reg;
      float v = fmaxf(acc[nf][reg] + b3[oc], 0.f);
      act3[(bt * 64 + oc) * 2304 + oh * 48 + ow] = f2bf(v);
    }
  }
}

// ============ deconv4 + tanh: act3 -> d_out fp32 [BT,3,96,96] ============
// per (frame, parity class); weights via wave-uniform s_loads
__global__ __launch_bounds__(256) void deconv4_kernel(
    const unsigned short* __restrict__ act3, const float* __restrict__ w4,
    const float* __restrict__ b4, float* __restrict__ out) {
  int cls = blockIdx.x, bt = blockIdx.y;
  int r = cls >> 1, s = cls & 1;
  const unsigned short* a3 = act3 + bt * 64 * 2304;
  float bias0 = b4[0], bias1 = b4[1], bias2 = b4[2];
#pragma unroll 1
  for (int it = 0; it < 9; it++) {
    int pix = it * 256 + threadIdx.x;  // (i,j) in 48x48 input grid
    int i = pix / 48, j = pix % 48;
    float acc0 = bias0, acc1 = bias1, acc2 = bias2;
#pragma unroll 1
    for (int ic = 0; ic < 64; ic++) {
      const unsigned short* ain = a3 + ic * 2304;
      const float* wic = w4 + ic * 48;  // [oc][kh][kw], uniform
#pragma unroll
      for (int a = 0; a < 2; a++) {
        int ih = i + r - a;
        bool okh = (ih >= 0) && (ih < 48);
        int kh = 2 * a + 1 - r;
#pragma unroll
        for (int bb = 0; bb < 2; bb++) {
          int iw = j + s - bb;
          bool ok = okh && (iw >= 0) && (iw < 48);
          float v = ok ? bf2f(ain[ih * 48 + iw]) : 0.f;
          int kw = 2 * bb + 1 - s;
          acc0 += v * wic[kh * 4 + kw];
          acc1 += v * wic[16 + kh * 4 + kw];
          acc2 += v * wic[32 + kh * 4 + kw];
        }
      }
    }
    int oh = 2 * i + r, ow = 2 * j + s;
    float* o = out + bt * 3 * 9216 + oh * 96 + ow;
    o[0] = tanhf(acc0);
    o[9216] = tanhf(acc1);
    o[18432] = tanhf(acc2);
  }
}

extern "C" void kernel_launch(void* const* d_in, const int* in_sizes, int n_in,
                              void* d_out, int out_size, void* d_ws, size_t ws_size,
                              hipStream_t stream) {
  const float* ident = (const float*)d_in[0];
  const float* lm = (const float*)d_in[1];
  const float* w1 = (const float*)d_in[2];
  const float* b1 = (const float*)d_in[3];
  const float* w2 = (const float*)d_in[4];
  const float* b2 = (const float*)d_in[5];
  const float* w3 = (const float*)d_in[6];
  const float* b3 = (const float*)d_in[7];
  const float* w4 = (const float*)d_in[8];
  const float* b4 = (const float*)d_in[9];
  float* out = (float*)d_out;
  char* ws = (char*)d_ws;
  unsigned short* hm = (unsigned short*)(ws + HM_OFF);
  unsigned short* act1 = (unsigned short*)(ws + ACT1_OFF);
  unsigned short* act2 = (unsigned short*)(ws + ACT2_OFF);
  unsigned short* act3 = (unsigned short*)(ws + ACT3_OFF);
  unsigned short* w2a = (unsigned short*)(ws + W2A_OFF);
  unsigned short* w3a = (unsigned short*)(ws + W3A_OFF);

  prep_kernel<<<dim3(384), 256, 0, stream>>>(lm, w2, w3, hm, w2a, w3a);
  conv1_kernel<<<dim3(9, 256), 256, 0, stream>>>(ident, hm, w1, b1, act1);
  conv2_kernel<<<dim3(9, 256), 256, 0, stream>>>(act1, w2a, b2, act2);
  deconv3_kernel<<<dim3(9, 4, 256), 256, 0, stream>>>(act2, w3a, b3, act3);
  deconv4_kernel<<<dim3(4, 256), 256, 0, stream>>>(act3, w4, b4, out);
}

// Round 2
// 665.522 us; speedup vs baseline: 1.7221x; 1.7221x over previous
//
#include <hip/hip_runtime.h>

// ---- workspace layout (bytes) ----
#define HM_OFF   0u
#define ACT1_OFF 4718592u                     // hm: 256*96*96*2
#define ACT2_OFF (ACT1_OFF + 75497472u)       // act1: 256*64*48*48*2
#define ACT3_OFF (ACT2_OFF + 37748736u)       // act2: 256*128*24*24*2
#define W2A_OFF  (ACT3_OFF + 75497472u)       // act3: 256*64*48*48*2
#define W3A_OFF  (W2A_OFF + 262144u)          // w2a: 128*1024*2

using short8  = __attribute__((ext_vector_type(8))) short;
using floatx4 = __attribute__((ext_vector_type(4))) float;

static __device__ __forceinline__ float bf2f(unsigned short u) {
  union { unsigned int i; float f; } v; v.i = ((unsigned int)u) << 16; return v.f;
}
static __device__ __forceinline__ unsigned short f2bf(float f) {
  union { float f; unsigned int i; } v; v.f = f;
  unsigned int x = v.i;
  return (unsigned short)((x + 0x7FFFu + ((x >> 16) & 1u)) >> 16);  // RNE
}
static __device__ __forceinline__ uint4 pack8(const unsigned short* v) {
  uint4 p;
  p.x = (unsigned)v[0] | ((unsigned)v[1] << 16);
  p.y = (unsigned)v[2] | ((unsigned)v[3] << 16);
  p.z = (unsigned)v[4] | ((unsigned)v[5] << 16);
  p.w = (unsigned)v[6] | ((unsigned)v[7] << 16);
  return p;
}
static __device__ __forceinline__ float ftanh(float x) {
  x = fminf(fmaxf(x, -10.f), 10.f);
  float e = __expf(2.f * x);
  return (e - 1.f) * __builtin_amdgcn_rcpf(e + 1.f);
}

// ============ prep: heatmap build + weight casts ============
__global__ __launch_bounds__(256) void prep_kernel(
    const float* __restrict__ lm, const float* __restrict__ w2,
    const float* __restrict__ w3,
    unsigned short* __restrict__ hm, unsigned short* __restrict__ w2a,
    unsigned short* __restrict__ w3a) {
  int bid = blockIdx.x, tid = threadIdx.x;
  if (bid < 256) {
    unsigned int* hm32 = (unsigned int*)(hm + bid * 9216);
    for (int i = tid; i < 4608; i += 256) hm32[i] = 0u;
    __syncthreads();
    if (tid < 68) {
      float x = lm[bid * 136 + tid * 2 + 0] * 95.0f;
      float y = lm[bid * 136 + tid * 2 + 1] * 95.0f;
      int ix = (int)x, iy = (int)y;
      if (ix >= 0 && ix < 96 && iy >= 0 && iy < 96)
        hm[bid * 9216 + iy * 96 + ix] = 0x3F80;  // bf16 1.0
    }
  } else if (bid < 320) {
    int e = (bid - 256) * 2048 + tid * 8;  // w2 flat [128][1024]
    float4 f0 = *(const float4*)(w2 + e);
    float4 f1 = *(const float4*)(w2 + e + 4);
    unsigned short v[8] = { f2bf(f0.x), f2bf(f0.y), f2bf(f0.z), f2bf(f0.w),
                            f2bf(f1.x), f2bf(f1.y), f2bf(f1.z), f2bf(f1.w) };
    *(uint4*)(w2a + e) = pack8(v);
  } else {
    int e = (bid - 320) * 2048 + tid * 8;  // w3a [cls][oc64][k512], k = ic*4+a*2+b
    unsigned short v[8];
#pragma unroll
    for (int j = 0; j < 8; j++) {
      int k = e + j;
      int c = k >> 15, rem = k & 32767;
      int oc = rem >> 9, kk = rem & 511;
      int ic = kk >> 2, a = (kk >> 1) & 1, b = kk & 1;
      int r = c >> 1, s = c & 1;
      int kh = 2 * a + 1 - r, kw = 2 * b + 1 - s;
      v[j] = f2bf(w3[((ic * 64 + oc) * 4 + kh) * 4 + kw]);
    }
    *(uint4*)(w3a + e) = pack8(v);
  }
}

// ============ conv1: [BT,4,96,96] -> relu -> act1 bf16 [BT,64,48,48] ============
__global__ __launch_bounds__(256) void conv1_kernel(
    const float* __restrict__ ident, const unsigned short* __restrict__ hm,
    const float* __restrict__ w1, const float* __restrict__ b1,
    unsigned short* __restrict__ act1) {
  int bt = blockIdx.y;
  int p = blockIdx.x * 256 + threadIdx.x;
  int oh = p / 48, ow = p % 48;
  int b = bt >> 5;
  float in_reg[64];
#pragma unroll
  for (int ic = 0; ic < 3; ic++) {
    const float* src = ident + (b * 3 + ic) * 9216;
#pragma unroll
    for (int kh = 0; kh < 4; kh++) {
      int ih = 2 * oh + kh - 1;
#pragma unroll
      for (int kw = 0; kw < 4; kw++) {
        int iw = 2 * ow + kw - 1;
        bool ok = (ih >= 0) && (ih < 96) && (iw >= 0) && (iw < 96);
        in_reg[ic * 16 + kh * 4 + kw] = ok ? src[ih * 96 + iw] : 0.0f;
      }
    }
  }
  {
    const unsigned short* hsrc = hm + bt * 9216;
#pragma unroll
    for (int kh = 0; kh < 4; kh++) {
      int ih = 2 * oh + kh - 1;
#pragma unroll
      for (int kw = 0; kw < 4; kw++) {
        int iw = 2 * ow + kw - 1;
        bool ok = (ih >= 0) && (ih < 96) && (iw >= 0) && (iw < 96);
        in_reg[48 + kh * 4 + kw] = ok ? bf2f(hsrc[ih * 96 + iw]) : 0.0f;
      }
    }
  }
  unsigned short* dst = act1 + bt * 64 * 2304 + p;
#pragma unroll 1
  for (int oc = 0; oc < 64; oc++) {
    float a0 = 0.f, a1 = 0.f, a2 = 0.f, a3 = 0.f;
    const float* wrow = w1 + oc * 64;
#pragma unroll
    for (int t = 0; t < 64; t += 4) {
      a0 += in_reg[t + 0] * wrow[t + 0];
      a1 += in_reg[t + 1] * wrow[t + 1];
      a2 += in_reg[t + 2] * wrow[t + 2];
      a3 += in_reg[t + 3] * wrow[t + 3];
    }
    float acc = b1[oc] + ((a0 + a1) + (a2 + a3));
    dst[oc * 2304] = f2bf(fmaxf(acc, 0.0f));
  }
}

// ============ conv2 (MFMA): act1 -> relu -> act2 bf16 [BT,128,24,24] ============
__global__ __launch_bounds__(256) void conv2_kernel(
    const unsigned short* __restrict__ act1, const unsigned short* __restrict__ w2a,
    const float* __restrict__ b2, unsigned short* __restrict__ act2) {
  __shared__ unsigned short Alds[128 * 32];
  __shared__ unsigned short Blds[64 * 32];
  int tid = threadIdx.x;
  int nb = blockIdx.x, bt = blockIdx.y;
  int wave = tid >> 6, lane = tid & 63, quad = lane >> 4, l16 = lane & 15;
  int nB = tid & 63, kg = tid >> 6;
  int pB = nb * 64 + nB;
  int ohB = pB / 24, owB = pB % 24;
  const unsigned short* a1 = act1 + bt * 64 * 2304;

  floatx4 acc[2][4];
#pragma unroll
  for (int i = 0; i < 2; i++)
#pragma unroll
    for (int j = 0; j < 4; j++) acc[i][j] = (floatx4){0.f, 0.f, 0.f, 0.f};

  for (int kk = 0; kk < 32; kk++) {
    uint4 av[2];
#pragma unroll
    for (int v = 0; v < 2; v++) {
      int e = v * 2048 + tid * 8;
      int row = e >> 5, kin = e & 31;
      av[v] = *(const uint4*)(w2a + row * 1024 + kk * 32 + kin);
    }
    unsigned short vals[8];
    int k0 = kk * 32 + kg * 8;
    int ic = k0 >> 4;
    int rr = k0 & 15;
#pragma unroll
    for (int j = 0; j < 8; j++) {
      int r2 = rr + j;
      int kh = r2 >> 2, kw = r2 & 3;
      int ih = 2 * ohB + kh - 1, iw = 2 * owB + kw - 1;
      bool ok = (ih >= 0) && (ih < 48) && (iw >= 0) && (iw < 48);
      vals[j] = ok ? a1[ic * 2304 + ih * 48 + iw] : (unsigned short)0;
    }
    __syncthreads();
#pragma unroll
    for (int v = 0; v < 2; v++) {
      int e = v * 2048 + tid * 8;
      *(uint4*)(Alds + e) = av[v];
    }
    *(uint4*)(Blds + nB * 32 + kg * 8) = pack8(vals);
    __syncthreads();
    short8 bfrag[4];
#pragma unroll
    for (int nf = 0; nf < 4; nf++)
      bfrag[nf] = *(const short8*)(Blds + (nf * 16 + l16) * 32 + quad * 8);
#pragma unroll
    for (int mf = 0; mf < 2; mf++) {
      int m = wave * 32 + mf * 16 + l16;
      short8 afrag = *(const short8*)(Alds + m * 32 + quad * 8);
#pragma unroll
      for (int nf = 0; nf < 4; nf++)
        acc[mf][nf] = __builtin_amdgcn_mfma_f32_16x16x32_bf16(afrag, bfrag[nf], acc[mf][nf], 0, 0, 0);
    }
  }
#pragma unroll
  for (int mf = 0; mf < 2; mf++) {
#pragma unroll
    for (int nf = 0; nf < 4; nf++) {
      int p = nb * 64 + nf * 16 + l16;
#pragma unroll
      for (int reg = 0; reg < 4; reg++) {
        int oc = wave * 32 + mf * 16 + quad * 4 + reg;
        float v = acc[mf][nf][reg] + b2[oc];
        act2[(bt * 128 + oc) * 576 + p] = f2bf(fmaxf(v, 0.f));
      }
    }
  }
}

// ============ deconv3 (MFMA): act2 -> relu -> act3 bf16 [BT,64,48,48] ============
__global__ __launch_bounds__(256) void deconv3_kernel(
    const unsigned short* __restrict__ act2, const unsigned short* __restrict__ w3a,
    const float* __restrict__ b3, unsigned short* __restrict__ act3) {
  __shared__ unsigned short Alds[64 * 32];
  __shared__ unsigned short Blds[64 * 32];
  int tid = threadIdx.x;
  int nb = blockIdx.x, cls = blockIdx.y, bt = blockIdx.z;
  int r = cls >> 1, s = cls & 1;
  int wave = tid >> 6, lane = tid & 63, quad = lane >> 4, l16 = lane & 15;
  int nB = tid & 63, kg = tid >> 6;
  int pB = nb * 64 + nB;
  int iB = pB / 24, jB = pB % 24;
  const unsigned short* a2 = act2 + bt * 128 * 576;
  const unsigned short* Ag = w3a + cls * 64 * 512;

  floatx4 acc[4];
#pragma unroll
  for (int j = 0; j < 4; j++) acc[j] = (floatx4){0.f, 0.f, 0.f, 0.f};

  for (int kk = 0; kk < 16; kk++) {
    int e = tid * 8, row = e >> 5, kin = e & 31;
    uint4 av = *(const uint4*)(Ag + row * 512 + kk * 32 + kin);
    unsigned short vals[8];
    int k0 = kk * 32 + kg * 8;
#pragma unroll
    for (int j = 0; j < 8; j++) {
      int k = k0 + j;
      int ic = k >> 2, a = (k >> 1) & 1, bb = k & 1;
      int ih = iB + r - a, iw = jB + s - bb;
      bool ok = (ih >= 0) && (ih < 24) && (iw >= 0) && (iw < 24);
      vals[j] = ok ? a2[ic * 576 + ih * 24 + iw] : (unsigned short)0;
    }
    __syncthreads();
    *(uint4*)(Alds + e) = av;
    *(uint4*)(Blds + nB * 32 + kg * 8) = pack8(vals);
    __syncthreads();
    short8 afrag = *(const short8*)(Alds + (wave * 16 + l16) * 32 + quad * 8);
#pragma unroll
    for (int nf = 0; nf < 4; nf++) {
      short8 bfrag = *(const short8*)(Blds + (nf * 16 + l16) * 32 + quad * 8);
      acc[nf] = __builtin_amdgcn_mfma_f32_16x16x32_bf16(afrag, bfrag, acc[nf], 0, 0, 0);
    }
  }
#pragma unroll
  for (int nf = 0; nf < 4; nf++) {
    int p = nb * 64 + nf * 16 + l16;
    int i = p / 24, j = p % 24;
    int oh = 2 * i + r, ow = 2 * j + s;
#pragma unroll
    for (int reg = 0; reg < 4; reg++) {
      int oc = wave * 16 + quad * 4 + reg;
      float v = fmaxf(acc[nf][reg] + b3[oc], 0.f);
      act3[(bt * 64 + oc) * 2304 + oh * 48 + ow] = f2bf(v);
    }
  }
}

// ============ deconv4 + tanh (v2, LDS-staged): act3 -> out fp32 [BT,3,96,96] ============
// grid (r=2, bt=256). Block pairs s=0/s=1 classes (share taps). 16 chunks of 4 ic
// staged in LDS; invalid taps point at zeroed LDS pad; weights via SGPR s_loads.
__global__ __launch_bounds__(256, 2) void deconv4_kernel(
    const unsigned short* __restrict__ act3, const float* __restrict__ w4,
    const float* __restrict__ b4, float* __restrict__ out) {
  __shared__ uint4 s4[2048];  // 32768 B: [0,18432) act chunk, pad zeros at 18432+icl*4608
  char* lds = (char*)s4;
  int tid = threadIdx.x;
  int r = blockIdx.x, bt = blockIdx.y;

  if (tid < 4) *(unsigned short*)(lds + 18432 + tid * 4608) = 0;

  // per-pixel tap base addresses (bytes into LDS act area), 6 per pixel
  int base[9][6];
#pragma unroll
  for (int it = 0; it < 9; it++) {
    int px = it * 256 + tid;
    int i = px / 48, j = px % 48;
    int ih0 = i + r;       // a=0
    int ih1 = i + r - 1;   // a=1
    bool r0 = (ih0 >= 0) && (ih0 < 48);
    bool r1 = (ih1 >= 0) && (ih1 < 48);
    bool c0 = (j - 1) >= 0;
    bool c2 = (j + 1) < 48;
#pragma unroll
    for (int c = 0; c < 3; c++) {
      int iw = j - 1 + c;
      bool cok = (c == 0) ? c0 : ((c == 2) ? c2 : true);
      base[it][c]     = (r0 && cok) ? (ih0 * 48 + iw) * 2 : 18432;
      base[it][3 + c] = (r1 && cok) ? (ih1 * 48 + iw) * 2 : 18432;
    }
  }

  float acc[9][2][3];
#pragma unroll
  for (int it = 0; it < 9; it++)
#pragma unroll
    for (int s = 0; s < 2; s++)
#pragma unroll
      for (int oc = 0; oc < 3; oc++) acc[it][s][oc] = 0.f;

  const uint4* gsrc = (const uint4*)((const char*)act3 + (size_t)bt * 294912u);
  uint4 pre[5];
  // prefetch chunk 0
#pragma unroll
  for (int v = 0; v < 4; v++) pre[v] = gsrc[v * 256 + tid];
  pre[4] = (tid < 128) ? gsrc[1024 + tid] : (uint4){0, 0, 0, 0};

  int kh0 = 1 - r, kh1 = 3 - r;

  for (int ch = 0; ch < 16; ch++) {
    __syncthreads();  // prior compute done with LDS
#pragma unroll
    for (int v = 0; v < 4; v++) s4[v * 256 + tid] = pre[v];
    if (tid < 128) s4[1024 + tid] = pre[4];
    __syncthreads();
    if (ch < 15) {
      const uint4* g = gsrc + (ch + 1) * 1152;
#pragma unroll
      for (int v = 0; v < 4; v++) pre[v] = g[v * 256 + tid];
      if (tid < 128) pre[4] = g[1024 + tid];
    }
#pragma unroll
    for (int icl = 0; icl < 4; icl++) {
      const float* wic = w4 + (ch * 4 + icl) * 48;
      float W0[3][4], W1[3][4];
#pragma unroll
      for (int oc = 0; oc < 3; oc++)
#pragma unroll
        for (int kw = 0; kw < 4; kw++) {
          W0[oc][kw] = wic[oc * 16 + kh0 * 4 + kw];
          W1[oc][kw] = wic[oc * 16 + kh1 * 4 + kw];
        }
      const char* lb = lds + icl * 4608;
#pragma unroll
      for (int it = 0; it < 9; it++) {
        float v0c0 = bf2f(*(const unsigned short*)(lb + base[it][0]));
        float v0c1 = bf2f(*(const unsigned short*)(lb + base[it][1]));
        float v0c2 = bf2f(*(const unsigned short*)(lb + base[it][2]));
        float v1c0 = bf2f(*(const unsigned short*)(lb + base[it][3]));
        float v1c1 = bf2f(*(const unsigned short*)(lb + base[it][4]));
        float v1c2 = bf2f(*(const unsigned short*)(lb + base[it][5]));
#pragma unroll
        for (int oc = 0; oc < 3; oc++) {
          acc[it][0][oc] += v0c1 * W0[oc][1] + v0c0 * W0[oc][3]
                          + v1c1 * W1[oc][1] + v1c0 * W1[oc][3];
          acc[it][1][oc] += v0c2 * W0[oc][0] + v0c1 * W0[oc][2]
                          + v1c2 * W1[oc][0] + v1c1 * W1[oc][2];
        }
      }
    }
  }

  float bias[3] = { b4[0], b4[1], b4[2] };
#pragma unroll
  for (int it = 0; it < 9; it++) {
    int px = it * 256 + tid;
    int i = px / 48, j = px % 48;
    int oh = 2 * i + r;
#pragma unroll
    for (int oc = 0; oc < 3; oc++) {
      float2 o;
      o.x = ftanh(acc[it][0][oc] + bias[oc]);
      o.y = ftanh(acc[it][1][oc] + bias[oc]);
      *(float2*)(out + (size_t)bt * 27648 + oc * 9216 + oh * 96 + 2 * j) = o;
    }
  }
}

extern "C" void kernel_launch(void* const* d_in, const int* in_sizes, int n_in,
                              void* d_out, int out_size, void* d_ws, size_t ws_size,
                              hipStream_t stream) {
  const float* ident = (const float*)d_in[0];
  const float* lm = (const float*)d_in[1];
  const float* w1 = (const float*)d_in[2];
  const float* b1 = (const float*)d_in[3];
  const float* w2 = (const float*)d_in[4];
  const float* b2 = (const float*)d_in[5];
  const float* w3 = (const float*)d_in[6];
  const float* b3 = (const float*)d_in[7];
  const float* w4 = (const float*)d_in[8];
  const float* b4 = (const float*)d_in[9];
  float* out = (float*)d_out;
  char* ws = (char*)d_ws;
  unsigned short* hm = (unsigned short*)(ws + HM_OFF);
  unsigned short* act1 = (unsigned short*)(ws + ACT1_OFF);
  unsigned short* act2 = (unsigned short*)(ws + ACT2_OFF);
  unsigned short* act3 = (unsigned short*)(ws + ACT3_OFF);
  unsigned short* w2a = (unsigned short*)(ws + W2A_OFF);
  unsigned short* w3a = (unsigned short*)(ws + W3A_OFF);

  prep_kernel<<<dim3(384), 256, 0, stream>>>(lm, w2, w3, hm, w2a, w3a);
  conv1_kernel<<<dim3(9, 256), 256, 0, stream>>>(ident, hm, w1, b1, act1);
  conv2_kernel<<<dim3(9, 256), 256, 0, stream>>>(act1, w2a, b2, act2);
  deconv3_kernel<<<dim3(9, 4, 256), 256, 0, stream>>>(act2, w3a, b3, act3);
  deconv4_kernel<<<dim3(2, 256), 256, 0, stream>>>(act3, w4, b4, out);
}

// Round 3
// 615.325 us; speedup vs baseline: 1.8626x; 1.0816x over previous
//
#include <hip/hip_runtime.h>

// ---- workspace layout (bytes) ----
#define HM_OFF    0u
#define ACT1P_OFF 4718592u     // hm: 256*96*96*2
#define ACT2P_OFF 89915392u    // act1p: 256*64*50*52*2 = 85196800
#define ACT3_OFF  134217728u   // act2p: 256*26*26*128*2 = 44302336
#define W2A_OFF   209715200u   // act3: 256*64*48*48*2 = 75497472
#define W3A_OFF   209977344u   // w2a: 128*1024*2

using short8  = __attribute__((ext_vector_type(8))) short;
using floatx4 = __attribute__((ext_vector_type(4))) float;
union UV { uint4 u; short8 s; };

static __device__ __forceinline__ float bf2f(unsigned short u) {
  union { unsigned int i; float f; } v; v.i = ((unsigned int)u) << 16; return v.f;
}
static __device__ __forceinline__ unsigned short f2bf(float f) {
  union { float f; unsigned int i; } v; v.f = f;
  unsigned int x = v.i;
  return (unsigned short)((x + 0x7FFFu + ((x >> 16) & 1u)) >> 16);  // RNE
}
static __device__ __forceinline__ uint4 pack8(const unsigned short* v) {
  uint4 p;
  p.x = (unsigned)v[0] | ((unsigned)v[1] << 16);
  p.y = (unsigned)v[2] | ((unsigned)v[3] << 16);
  p.z = (unsigned)v[4] | ((unsigned)v[5] << 16);
  p.w = (unsigned)v[6] | ((unsigned)v[7] << 16);
  return p;
}
static __device__ __forceinline__ float ftanh(float x) {
  x = fminf(fmaxf(x, -10.f), 10.f);
  float e = __expf(2.f * x);
  return (e - 1.f) * __builtin_amdgcn_rcpf(e + 1.f);
}

// ============ prep: heatmap, weight casts, pad zeroing ============
__global__ __launch_bounds__(256) void prep_kernel(
    const float* __restrict__ lm, const float* __restrict__ w2,
    const float* __restrict__ w3,
    unsigned short* __restrict__ hm, unsigned short* __restrict__ w2a,
    unsigned short* __restrict__ w3a, unsigned short* __restrict__ act1p,
    unsigned short* __restrict__ act2p) {
  int bid = blockIdx.x, tid = threadIdx.x;
  if (bid < 256) {
    unsigned int* hm32 = (unsigned int*)(hm + bid * 9216);
    for (int i = tid; i < 4608; i += 256) hm32[i] = 0u;
    __syncthreads();
    if (tid < 68) {
      float x = lm[bid * 136 + tid * 2 + 0] * 95.0f;
      float y = lm[bid * 136 + tid * 2 + 1] * 95.0f;
      int ix = (int)x, iy = (int)y;
      if (ix >= 0 && ix < 96 && iy >= 0 && iy < 96)
        hm[bid * 9216 + iy * 96 + ix] = 0x3F80;  // bf16 1.0
    }
  } else if (bid < 320) {
    int e = (bid - 256) * 2048 + tid * 8;  // w2 flat [128][1024], k=ic*16+kh*4+kw
    float4 f0 = *(const float4*)(w2 + e);
    float4 f1 = *(const float4*)(w2 + e + 4);
    unsigned short v[8] = { f2bf(f0.x), f2bf(f0.y), f2bf(f0.z), f2bf(f0.w),
                            f2bf(f1.x), f2bf(f1.y), f2bf(f1.z), f2bf(f1.w) };
    *(uint4*)(w2a + e) = pack8(v);
  } else if (bid < 384) {
    int e = (bid - 320) * 2048 + tid * 8;  // w3a [cls][oc64][k512], k=(a*2+b)*128+ic
    unsigned short v[8];
#pragma unroll
    for (int j = 0; j < 8; j++) {
      int k = e + j;
      int cls = k >> 15, rem = k & 32767;
      int oc = rem >> 9, kidx = rem & 511;
      int ab = kidx >> 7, ic = kidx & 127;
      int a = ab >> 1, b = ab & 1;
      int r = cls >> 1, s = cls & 1;
      int kh = 2 * a + 1 - r, kw = 2 * b + 1 - s;
      v[j] = f2bf(w3[((ic * 64 + oc) * 4 + kh) * 4 + kw]);
    }
    *(uint4*)(w3a + e) = pack8(v);
  } else if (bid < 640) {
    // act1p halo zero, one block per frame: [ic][50][52], data rows1..48 cols1..48
    unsigned short* base = act1p + (bid - 384) * 166400;
    for (int idx = tid; idx < 18944; idx += 256) {
      int ic = idx / 296;
      int e = idx - ic * 296;
      int o;
      if (e < 53) o = e;                                     // row0 + row1 col0
      else if (e < 241) { int q = (e - 53) >> 2; int m = (e - 53) & 3;
                          o = (q + 1) * 52 + 49 + m; }       // right pads + next col0
      else o = 2545 + (e - 241);                             // row48 tail + row49
      base[ic * 2600 + o] = 0;
    }
  } else {
    // act2p halo zero, one block per frame: [26][26][128] channel-last
    uint4* b4p = (uint4*)(act2p + (size_t)(bid - 640) * 86528u);
    uint4 z = {0, 0, 0, 0};
    for (int c = tid; c < 1600; c += 256) {
      int cell = c >> 4, v = c & 15;
      int row, col;
      if (cell < 26) { row = 0; col = cell; }
      else if (cell < 52) { row = 25; col = cell - 26; }
      else if (cell < 76) { row = cell - 51; col = 0; }
      else { row = cell - 75; col = 25; }
      b4p[(row * 26 + col) * 16 + v] = z;
    }
  }
}

// ============ conv1: -> act1p bf16 [BT][64][50][52] (padded, +1 shift) ============
__global__ __launch_bounds__(256) void conv1_kernel(
    const float* __restrict__ ident, const unsigned short* __restrict__ hm,
    const float* __restrict__ w1, const float* __restrict__ b1,
    unsigned short* __restrict__ act1p) {
  int bt = blockIdx.y;
  int p = blockIdx.x * 256 + threadIdx.x;
  int oh = p / 48, ow = p % 48;
  int b = bt >> 5;
  float in_reg[64];
#pragma unroll
  for (int ic = 0; ic < 3; ic++) {
    const float* src = ident + (b * 3 + ic) * 9216;
#pragma unroll
    for (int kh = 0; kh < 4; kh++) {
      int ih = 2 * oh + kh - 1;
#pragma unroll
      for (int kw = 0; kw < 4; kw++) {
        int iw = 2 * ow + kw - 1;
        bool ok = (ih >= 0) && (ih < 96) && (iw >= 0) && (iw < 96);
        in_reg[ic * 16 + kh * 4 + kw] = ok ? src[ih * 96 + iw] : 0.0f;
      }
    }
  }
  {
    const unsigned short* hsrc = hm + bt * 9216;
#pragma unroll
    for (int kh = 0; kh < 4; kh++) {
      int ih = 2 * oh + kh - 1;
#pragma unroll
      for (int kw = 0; kw < 4; kw++) {
        int iw = 2 * ow + kw - 1;
        bool ok = (ih >= 0) && (ih < 96) && (iw >= 0) && (iw < 96);
        in_reg[48 + kh * 4 + kw] = ok ? bf2f(hsrc[ih * 96 + iw]) : 0.0f;
      }
    }
  }
  unsigned short* dst = act1p + (size_t)bt * 166400u + (oh + 1) * 52 + (ow + 1);
#pragma unroll 2
  for (int oc = 0; oc < 64; oc++) {
    float a0 = 0.f, a1 = 0.f, a2 = 0.f, a3 = 0.f;
    const float* wrow = w1 + oc * 64;
#pragma unroll
    for (int t = 0; t < 64; t += 4) {
      a0 += in_reg[t + 0] * wrow[t + 0];
      a1 += in_reg[t + 1] * wrow[t + 1];
      a2 += in_reg[t + 2] * wrow[t + 2];
      a3 += in_reg[t + 3] * wrow[t + 3];
    }
    float acc = b1[oc] + ((a0 + a1) + (a2 + a3));
    dst[oc * 2600] = f2bf(fmaxf(acc, 0.0f));
  }
}

// ============ conv2 (MFMA): act1p -> relu -> act2p [26][26][128] channel-last ============
// GEMM/frame: C[128][576] = w2a[128][1024] * im2col[1024][576]; block tile 128x64
// A frags direct global (L2-hot), B via ping-pong LDS stride-40, one barrier/K-step
__global__ __launch_bounds__(256) void conv2_kernel(
    const unsigned short* __restrict__ act1p, const unsigned short* __restrict__ w2a,
    const float* __restrict__ b2, unsigned short* __restrict__ act2p) {
  __shared__ unsigned short Blds[2][64 * 40];
  int tid = threadIdx.x;
  int nb = blockIdx.x, bt = blockIdx.y;
  int wave = tid >> 6, lane = tid & 63, quad = lane >> 4, l16 = lane & 15;
  int nB = tid & 63, g = tid >> 6;
  int icl = g >> 1, khp = g & 1;
  int pB = nb * 64 + nB;
  int ohB = pB / 24, owB = pB % 24;
  const unsigned short* gbase =
      act1p + (size_t)bt * 166400u + icl * 2600 + (2 * ohB + khp * 2) * 52 + 2 * owB;
  const unsigned short* aptr0 = w2a + (wave * 32 + l16) * 1024 + quad * 8;
  const unsigned short* aptr1 = aptr0 + 16 * 1024;

  floatx4 acc[2][4];
#pragma unroll
  for (int i = 0; i < 2; i++)
#pragma unroll
    for (int j = 0; j < 4; j++) acc[i][j] = (floatx4){0.f, 0.f, 0.f, 0.f};

  // prologue: gather kk=0 B, prefetch kk=0 A
  uint4 bv;
  bv.x = *(const unsigned int*)(gbase);
  bv.y = *(const unsigned int*)(gbase + 2);
  bv.z = *(const unsigned int*)(gbase + 52);
  bv.w = *(const unsigned int*)(gbase + 54);
  *(uint4*)(&Blds[0][nB * 40 + g * 8]) = bv;
  UV a_cur0, a_cur1, a_nxt0, a_nxt1;
  a_cur0.u = *(const uint4*)(aptr0);
  a_cur1.u = *(const uint4*)(aptr1);
  __syncthreads();

  for (int kk = 0; kk < 32; kk++) {
    int cur = kk & 1;
    UV bfrag[4];
#pragma unroll
    for (int nf = 0; nf < 4; nf++)
      bfrag[nf].u = *(const uint4*)(&Blds[cur][(nf * 16 + l16) * 40 + quad * 8]);
    uint4 bnv;
    if (kk < 31) {
      const unsigned short* p = gbase + (kk + 1) * 5200;  // 2 ic per K-step
      bnv.x = *(const unsigned int*)(p);
      bnv.y = *(const unsigned int*)(p + 2);
      bnv.z = *(const unsigned int*)(p + 52);
      bnv.w = *(const unsigned int*)(p + 54);
      a_nxt0.u = *(const uint4*)(aptr0 + (kk + 1) * 32);
      a_nxt1.u = *(const uint4*)(aptr1 + (kk + 1) * 32);
    }
#pragma unroll
    for (int nf = 0; nf < 4; nf++) {
      acc[0][nf] = __builtin_amdgcn_mfma_f32_16x16x32_bf16(a_cur0.s, bfrag[nf].s, acc[0][nf], 0, 0, 0);
      acc[1][nf] = __builtin_amdgcn_mfma_f32_16x16x32_bf16(a_cur1.s, bfrag[nf].s, acc[1][nf], 0, 0, 0);
    }
    if (kk < 31) *(uint4*)(&Blds[1 - cur][nB * 40 + g * 8]) = bnv;
    __syncthreads();
    a_cur0 = a_nxt0; a_cur1 = a_nxt1;
  }

  // epilogue: C row = quad*4+reg (oc), col = l16 (pixel); channel-last store, 8B runs
  unsigned short* obase = act2p + (size_t)bt * 86528u;
#pragma unroll
  for (int mf = 0; mf < 2; mf++) {
    int oc0 = wave * 32 + mf * 16 + quad * 4;
    float4 bb = *(const float4*)(b2 + oc0);
#pragma unroll
    for (int nf = 0; nf < 4; nf++) {
      int p = nb * 64 + nf * 16 + l16;
      int oh = p / 24, ow = p % 24;
      float v0 = fmaxf(acc[mf][nf][0] + bb.x, 0.f);
      float v1 = fmaxf(acc[mf][nf][1] + bb.y, 0.f);
      float v2 = fmaxf(acc[mf][nf][2] + bb.z, 0.f);
      float v3 = fmaxf(acc[mf][nf][3] + bb.w, 0.f);
      uint2 o;
      o.x = (unsigned)f2bf(v0) | ((unsigned)f2bf(v1) << 16);
      o.y = (unsigned)f2bf(v2) | ((unsigned)f2bf(v3) << 16);
      *(uint2*)(obase + ((oh + 1) * 26 + (ow + 1)) * 128 + oc0) = o;
    }
  }
}

// ============ deconv3 (MFMA): act2p -> relu -> act3 [BT][64][48][48] ============
// per (frame, r): both s classes fused. C_s[64][576] = w3a[r*2+s] * B_s[512][576]
// k = (a*2+b)*128 + ic; per K-step one (a,b), 32 ic; B gather = one dwordx4/thread/tile
__global__ __launch_bounds__(256) void deconv3_kernel(
    const unsigned short* __restrict__ act2p, const unsigned short* __restrict__ w3a,
    const float* __restrict__ b3, unsigned short* __restrict__ act3) {
  __shared__ unsigned short Blds[2][2][64 * 40];
  int tid = threadIdx.x;
  int nb = blockIdx.x, r = blockIdx.y, bt = blockIdx.z;
  int wave = tid >> 6, lane = tid & 63, quad = lane >> 4, l16 = lane & 15;
  int nB = tid & 63, g = tid >> 6;
  int pB = nb * 64 + nB;
  int iB = pB / 24, jB = pB % 24;
  const unsigned short* a2 = act2p + (size_t)bt * 86528u;
  const unsigned short* A0 = w3a + (r * 2) * 32768 + (wave * 16 + l16) * 512 + quad * 8;
  const unsigned short* A1 = A0 + 32768;

  floatx4 acc[2][4];
#pragma unroll
  for (int i = 0; i < 2; i++)
#pragma unroll
    for (int j = 0; j < 4; j++) acc[i][j] = (floatx4){0.f, 0.f, 0.f, 0.f};

  // prologue kk=0: ab=0 (a=0,b=0); row=iB+r+1, cols jB+1, jB+2
  {
    int row = iB + r + 1;
    const unsigned short* p = a2 + (row * 26 + jB + 1) * 128 + g * 8;
    uint4 b0 = *(const uint4*)(p);
    uint4 b1 = *(const uint4*)(p + 128);
    *(uint4*)(&Blds[0][0][nB * 40 + g * 8]) = b0;
    *(uint4*)(&Blds[0][1][nB * 40 + g * 8]) = b1;
  }
  UV a_cur0, a_cur1, a_nxt0, a_nxt1;
  a_cur0.u = *(const uint4*)(A0);
  a_cur1.u = *(const uint4*)(A1);
  __syncthreads();

  for (int kk = 0; kk < 16; kk++) {
    int cur = kk & 1;
    UV bfrag[2][4];
#pragma unroll
    for (int s = 0; s < 2; s++)
#pragma unroll
      for (int nf = 0; nf < 4; nf++)
        bfrag[s][nf].u = *(const uint4*)(&Blds[cur][s][(nf * 16 + l16) * 40 + quad * 8]);
    uint4 bn0, bn1;
    if (kk < 15) {
      int kn = kk + 1;
      int ab = kn >> 2, ic0 = (kn & 3) * 32;
      int a = ab >> 1, b = ab & 1;
      int row = iB + r - a + 1;
      const unsigned short* p = a2 + (row * 26 + jB + 1 - b) * 128 + ic0 + g * 8;
      bn0 = *(const uint4*)(p);
      bn1 = *(const uint4*)(p + 128);
      a_nxt0.u = *(const uint4*)(A0 + kn * 32);
      a_nxt1.u = *(const uint4*)(A1 + kn * 32);
    }
#pragma unroll
    for (int nf = 0; nf < 4; nf++) {
      acc[0][nf] = __builtin_amdgcn_mfma_f32_16x16x32_bf16(a_cur0.s, bfrag[0][nf].s, acc[0][nf], 0, 0, 0);
      acc[1][nf] = __builtin_amdgcn_mfma_f32_16x16x32_bf16(a_cur1.s, bfrag[1][nf].s, acc[1][nf], 0, 0, 0);
    }
    if (kk < 15) {
      *(uint4*)(&Blds[1 - cur][0][nB * 40 + g * 8]) = bn0;
      *(uint4*)(&Blds[1 - cur][1][nB * 40 + g * 8]) = bn1;
    }
    __syncthreads();
    a_cur0 = a_nxt0; a_cur1 = a_nxt1;
  }

  // epilogue: oc = wave*16+quad*4+reg; (oh, ow=2j|2j+1) paired -> uint stores
  float4 bb = *(const float4*)(b3 + wave * 16 + quad * 4);
#pragma unroll
  for (int nf = 0; nf < 4; nf++) {
    int n = nb * 64 + nf * 16 + l16;
    int i = n / 24, j = n % 24;
    int oh = 2 * i + r;
#pragma unroll
    for (int reg = 0; reg < 4; reg++) {
      int oc = wave * 16 + quad * 4 + reg;
      float bias = (reg == 0) ? bb.x : (reg == 1) ? bb.y : (reg == 2) ? bb.z : bb.w;
      float v0 = fmaxf(acc[0][nf][reg] + bias, 0.f);
      float v1 = fmaxf(acc[1][nf][reg] + bias, 0.f);
      unsigned int o = (unsigned)f2bf(v0) | ((unsigned)f2bf(v1) << 16);
      *(unsigned int*)(act3 + ((size_t)(bt * 64 + oc)) * 2304u + oh * 48 + 2 * j) = o;
    }
  }
}

// ============ deconv4 + tanh (LDS-staged): act3 -> out fp32 [BT,3,96,96] ============
__global__ __launch_bounds__(256, 2) void deconv4_kernel(
    const unsigned short* __restrict__ act3, const float* __restrict__ w4,
    const float* __restrict__ b4, float* __restrict__ out) {
  __shared__ uint4 s4[2048];  // 32768 B: [0,18432) act chunk, pad zeros at 18432+icl*4608
  char* lds = (char*)s4;
  int tid = threadIdx.x;
  int r = blockIdx.x, bt = blockIdx.y;

  if (tid < 4) *(unsigned short*)(lds + 18432 + tid * 4608) = 0;

  int base[9][6];
#pragma unroll
  for (int it = 0; it < 9; it++) {
    int px = it * 256 + tid;
    int i = px / 48, j = px % 48;
    int ih0 = i + r;
    int ih1 = i + r - 1;
    bool r0 = (ih0 >= 0) && (ih0 < 48);
    bool r1 = (ih1 >= 0) && (ih1 < 48);
    bool c0 = (j - 1) >= 0;
    bool c2 = (j + 1) < 48;
#pragma unroll
    for (int c = 0; c < 3; c++) {
      int iw = j - 1 + c;
      bool cok = (c == 0) ? c0 : ((c == 2) ? c2 : true);
      base[it][c]     = (r0 && cok) ? (ih0 * 48 + iw) * 2 : 18432;
      base[it][3 + c] = (r1 && cok) ? (ih1 * 48 + iw) * 2 : 18432;
    }
  }

  float acc[9][2][3];
#pragma unroll
  for (int it = 0; it < 9; it++)
#pragma unroll
    for (int s = 0; s < 2; s++)
#pragma unroll
      for (int oc = 0; oc < 3; oc++) acc[it][s][oc] = 0.f;

  const uint4* gsrc = (const uint4*)((const char*)act3 + (size_t)bt * 294912u);
  uint4 pre[5];
#pragma unroll
  for (int v = 0; v < 4; v++) pre[v] = gsrc[v * 256 + tid];
  pre[4] = (tid < 128) ? gsrc[1024 + tid] : (uint4){0, 0, 0, 0};

  int kh0 = 1 - r, kh1 = 3 - r;

  for (int ch = 0; ch < 16; ch++) {
    __syncthreads();
#pragma unroll
    for (int v = 0; v < 4; v++) s4[v * 256 + tid] = pre[v];
    if (tid < 128) s4[1024 + tid] = pre[4];
    __syncthreads();
    if (ch < 15) {
      const uint4* gq = gsrc + (ch + 1) * 1152;
#pragma unroll
      for (int v = 0; v < 4; v++) pre[v] = gq[v * 256 + tid];
      if (tid < 128) pre[4] = gq[1024 + tid];
    }
#pragma unroll
    for (int icl = 0; icl < 4; icl++) {
      const float* wic = w4 + (ch * 4 + icl) * 48;
      float W0[3][4], W1[3][4];
#pragma unroll
      for (int oc = 0; oc < 3; oc++)
#pragma unroll
        for (int kw = 0; kw < 4; kw++) {
          W0[oc][kw] = wic[oc * 16 + kh0 * 4 + kw];
          W1[oc][kw] = wic[oc * 16 + kh1 * 4 + kw];
        }
      const char* lb = lds + icl * 4608;
#pragma unroll
      for (int it = 0; it < 9; it++) {
        float v0c0 = bf2f(*(const unsigned short*)(lb + base[it][0]));
        float v0c1 = bf2f(*(const unsigned short*)(lb + base[it][1]));
        float v0c2 = bf2f(*(const unsigned short*)(lb + base[it][2]));
        float v1c0 = bf2f(*(const unsigned short*)(lb + base[it][3]));
        float v1c1 = bf2f(*(const unsigned short*)(lb + base[it][4]));
        float v1c2 = bf2f(*(const unsigned short*)(lb + base[it][5]));
#pragma unroll
        for (int oc = 0; oc < 3; oc++) {
          acc[it][0][oc] += v0c1 * W0[oc][1] + v0c0 * W0[oc][3]
                          + v1c1 * W1[oc][1] + v1c0 * W1[oc][3];
          acc[it][1][oc] += v0c2 * W0[oc][0] + v0c1 * W0[oc][2]
                          + v1c2 * W1[oc][0] + v1c1 * W1[oc][2];
        }
      }
    }
  }

  float bias[3] = { b4[0], b4[1], b4[2] };
#pragma unroll
  for (int it = 0; it < 9; it++) {
    int px = it * 256 + tid;
    int i = px / 48, j = px % 48;
    int oh = 2 * i + r;
#pragma unroll
    for (int oc = 0; oc < 3; oc++) {
      float2 o;
      o.x = ftanh(acc[it][0][oc] + bias[oc]);
      o.y = ftanh(acc[it][1][oc] + bias[oc]);
      *(float2*)(out + (size_t)bt * 27648 + oc * 9216 + oh * 96 + 2 * j) = o;
    }
  }
}

extern "C" void kernel_launch(void* const* d_in, const int* in_sizes, int n_in,
                              void* d_out, int out_size, void* d_ws, size_t ws_size,
                              hipStream_t stream) {
  const float* ident = (const float*)d_in[0];
  const float* lm = (const float*)d_in[1];
  const float* w1 = (const float*)d_in[2];
  const float* b1 = (const float*)d_in[3];
  const float* w2 = (const float*)d_in[4];
  const float* b2 = (const float*)d_in[5];
  const float* w3 = (const float*)d_in[6];
  const float* b3 = (const float*)d_in[7];
  const float* w4 = (const float*)d_in[8];
  const float* b4 = (const float*)d_in[9];
  float* out = (float*)d_out;
  char* ws = (char*)d_ws;
  unsigned short* hm = (unsigned short*)(ws + HM_OFF);
  unsigned short* act1p = (unsigned short*)(ws + ACT1P_OFF);
  unsigned short* act2p = (unsigned short*)(ws + ACT2P_OFF);
  unsigned short* act3 = (unsigned short*)(ws + ACT3_OFF);
  unsigned short* w2a = (unsigned short*)(ws + W2A_OFF);
  unsigned short* w3a = (unsigned short*)(ws + W3A_OFF);

  prep_kernel<<<dim3(896), 256, 0, stream>>>(lm, w2, w3, hm, w2a, w3a, act1p, act2p);
  conv1_kernel<<<dim3(9, 256), 256, 0, stream>>>(ident, hm, w1, b1, act1p);
  conv2_kernel<<<dim3(9, 256), 256, 0, stream>>>(act1p, w2a, b2, act2p);
  deconv3_kernel<<<dim3(9, 2, 256), 256, 0, stream>>>(act2p, w3a, b3, act3);
  deconv4_kernel<<<dim3(2, 256), 256, 0, stream>>>(act3, w4, b4, out);
}

// Round 4
// 495.489 us; speedup vs baseline: 2.3131x; 1.2419x over previous
//
#include <hip/hip_runtime.h>

// ---- workspace layout (bytes) ----
#define IDENTP_OFF 0u            // identp: 8*3*98*100*2 = 470400
#define HMP_OFF    470400u       // hmp: 256*98*100*2 = 5017600
#define ACT1P_OFF  5488000u      // act1p: 256*64*50*52*2 = 85196800
#define ACT2P_OFF  90684800u     // act2p: 256*26*26*128*2 = 44302336
#define ACT3_OFF   134987136u    // act3: 256*64*48*48*2 = 75497472
#define W2A_OFF    210484608u    // w2a: 128*1024*2 = 262144
#define W3A_OFF    210746752u    // w3a: 4*64*512*2 = 262144
#define W1B_OFF    211008896u    // w1b: 64*64*2 = 8192

using short8  = __attribute__((ext_vector_type(8))) short;
using floatx4 = __attribute__((ext_vector_type(4))) float;
union UV { uint4 u; short8 s; };

static __device__ __forceinline__ float bf2f(unsigned short u) {
  union { unsigned int i; float f; } v; v.i = ((unsigned int)u) << 16; return v.f;
}
static __device__ __forceinline__ unsigned short f2bf(float f) {
  union { float f; unsigned int i; } v; v.f = f;
  unsigned int x = v.i;
  return (unsigned short)((x + 0x7FFFu + ((x >> 16) & 1u)) >> 16);  // RNE
}
static __device__ __forceinline__ uint4 pack8(const unsigned short* v) {
  uint4 p;
  p.x = (unsigned)v[0] | ((unsigned)v[1] << 16);
  p.y = (unsigned)v[2] | ((unsigned)v[3] << 16);
  p.z = (unsigned)v[4] | ((unsigned)v[5] << 16);
  p.w = (unsigned)v[6] | ((unsigned)v[7] << 16);
  return p;
}
static __device__ __forceinline__ float ftanh(float x) {
  x = fminf(fmaxf(x, -10.f), 10.f);
  float e = __expf(2.f * x);
  return (e - 1.f) * __builtin_amdgcn_rcpf(e + 1.f);
}

// ============ prep: heatmap(padded), identp, weight casts, pad zeroing ============
__global__ __launch_bounds__(256) void prep_kernel(
    const float* __restrict__ lm, const float* __restrict__ ident,
    const float* __restrict__ w1, const float* __restrict__ w2,
    const float* __restrict__ w3,
    unsigned short* __restrict__ identp, unsigned short* __restrict__ hmp,
    unsigned short* __restrict__ w1b, unsigned short* __restrict__ w2a,
    unsigned short* __restrict__ w3a, unsigned short* __restrict__ act1p,
    unsigned short* __restrict__ act2p) {
  int bid = blockIdx.x, tid = threadIdx.x;
  if (bid < 256) {
    // hmp [bt][98][100]: zero then scatter landmarks at (+1,+1)
    unsigned int* h32 = (unsigned int*)(hmp + bid * 9800);
    for (int i = tid; i < 4900; i += 256) h32[i] = 0u;
    __syncthreads();
    if (tid < 68) {
      float x = lm[bid * 136 + tid * 2 + 0] * 95.0f;
      float y = lm[bid * 136 + tid * 2 + 1] * 95.0f;
      int ix = (int)x, iy = (int)y;
      if (ix >= 0 && ix < 96 && iy >= 0 && iy < 96)
        hmp[bid * 9800 + (iy + 1) * 100 + (ix + 1)] = 0x3F80;  // bf16 1.0
    }
  } else if (bid < 320) {
    int e = (bid - 256) * 2048 + tid * 8;  // w2 flat [128][1024], k=ic*16+kh*4+kw
    float4 f0 = *(const float4*)(w2 + e);
    float4 f1 = *(const float4*)(w2 + e + 4);
    unsigned short v[8] = { f2bf(f0.x), f2bf(f0.y), f2bf(f0.z), f2bf(f0.w),
                            f2bf(f1.x), f2bf(f1.y), f2bf(f1.z), f2bf(f1.w) };
    *(uint4*)(w2a + e) = pack8(v);
  } else if (bid < 384) {
    int e = (bid - 320) * 2048 + tid * 8;  // w3a [cls][oc64][k512], k=(a*2+b)*128+ic
    unsigned short v[8];
#pragma unroll
    for (int j = 0; j < 8; j++) {
      int k = e + j;
      int cls = k >> 15, rem = k & 32767;
      int oc = rem >> 9, kidx = rem & 511;
      int ab = kidx >> 7, ic = kidx & 127;
      int a = ab >> 1, b = ab & 1;
      int r = cls >> 1, s = cls & 1;
      int kh = 2 * a + 1 - r, kw = 2 * b + 1 - s;
      v[j] = f2bf(w3[((ic * 64 + oc) * 4 + kh) * 4 + kw]);
    }
    *(uint4*)(w3a + e) = pack8(v);
  } else if (bid < 408) {
    // identp [b*3+ic][98][100] bf16, interior rows/cols 1..96
    int bci = bid - 384;
    const float* src = ident + bci * 9216;
    unsigned short* dst = identp + bci * 9800;
    for (int i = tid; i < 9800; i += 256) {
      int row = i / 100, col = i - row * 100;
      bool in = (row >= 1) && (row <= 96) && (col >= 1) && (col <= 96);
      dst[i] = in ? f2bf(src[(row - 1) * 96 + (col - 1)]) : (unsigned short)0;
    }
  } else if (bid < 664) {
    // act1p halo zero, one block per frame: [ic][50][52], data rows1..48 cols1..48
    unsigned short* base = act1p + (size_t)(bid - 408) * 166400u;
    for (int idx = tid; idx < 18944; idx += 256) {
      int ic = idx / 296;
      int e = idx - ic * 296;
      int o;
      if (e < 53) o = e;
      else if (e < 241) { int q = (e - 53) >> 2; int m = (e - 53) & 3;
                          o = (q + 1) * 52 + 49 + m; }
      else o = 2545 + (e - 241);
      base[ic * 2600 + o] = 0;
    }
  } else if (bid < 920) {
    // act2p halo zero, one block per frame: [26][26][128] channel-last
    uint4* b4p = (uint4*)(act2p + (size_t)(bid - 664) * 86528u);
    uint4 z = {0, 0, 0, 0};
    for (int c = tid; c < 1600; c += 256) {
      int cell = c >> 4, v = c & 15;
      int row, col;
      if (cell < 26) { row = 0; col = cell; }
      else if (cell < 52) { row = 25; col = cell - 26; }
      else if (cell < 76) { row = cell - 51; col = 0; }
      else { row = cell - 75; col = 25; }
      b4p[(row * 26 + col) * 16 + v] = z;
    }
  } else {
    // w1b [64][64] bf16 (w1 flat is already [oc][ic*16+kh*4+kw])
    int e = tid * 16;
    unsigned short v[16];
#pragma unroll
    for (int q = 0; q < 4; q++) {
      float4 f = *(const float4*)(w1 + e + q * 4);
      v[q * 4 + 0] = f2bf(f.x); v[q * 4 + 1] = f2bf(f.y);
      v[q * 4 + 2] = f2bf(f.z); v[q * 4 + 3] = f2bf(f.w);
    }
    *(uint4*)(w1b + e) = pack8(v);
    *(uint4*)(w1b + e + 8) = pack8(v + 8);
  }
}

// ============ conv1 (MFMA): identp+hmp -> relu -> act1p [BT][64][50][52] ============
// GEMM/frame: C[64][2304] = w1b[64][64] * im2col[64][2304]; block N=64, K=64 (2 steps)
__global__ __launch_bounds__(256) void conv1_kernel(
    const unsigned short* __restrict__ identp, const unsigned short* __restrict__ hmp,
    const unsigned short* __restrict__ w1b, const float* __restrict__ b1,
    unsigned short* __restrict__ act1p) {
  __shared__ unsigned short Blds[64 * 72];  // [n][k64 + pad8]
  int tid = threadIdx.x;
  int nb = blockIdx.x, bt = blockIdx.y;
  int b = bt >> 5;
  int wave = tid >> 6, lane = tid & 63, quad = lane >> 4, l16 = lane & 15;
  int nB = tid & 63, g = tid >> 6;
  int pB = nb * 64 + nB;
  int ohB = pB / 48, owB = pB % 48;

  // gather both K-steps: k0 = ks*32 + g*8; ic = k0>>4; khp = (k0>>3)&1
#pragma unroll
  for (int ks = 0; ks < 2; ks++) {
    int k0 = ks * 32 + g * 8;
    int ic = k0 >> 4, khp = (k0 >> 3) & 1;
    const unsigned short* src = (ic < 3) ? identp + (b * 3 + ic) * 9800
                                         : hmp + bt * 9800;
    const unsigned short* p = src + (2 * ohB + khp * 2) * 100 + 2 * owB;
    uint4 bv;
    bv.x = *(const unsigned int*)(p);
    bv.y = *(const unsigned int*)(p + 2);
    bv.z = *(const unsigned int*)(p + 100);
    bv.w = *(const unsigned int*)(p + 102);
    *(uint4*)(&Blds[nB * 72 + k0]) = bv;
  }
  // A fragments (w1b is 8KB, L2-hot)
  const unsigned short* aptr = w1b + (wave * 16 + l16) * 64 + quad * 8;
  UV a0, a1;
  a0.u = *(const uint4*)(aptr);
  a1.u = *(const uint4*)(aptr + 32);
  __syncthreads();

  floatx4 acc[4];
#pragma unroll
  for (int nf = 0; nf < 4; nf++) acc[nf] = (floatx4){0.f, 0.f, 0.f, 0.f};
#pragma unroll
  for (int nf = 0; nf < 4; nf++) {
    UV b0, b1v;
    b0.u = *(const uint4*)(&Blds[(nf * 16 + l16) * 72 + quad * 8]);
    b1v.u = *(const uint4*)(&Blds[(nf * 16 + l16) * 72 + 32 + quad * 8]);
    acc[nf] = __builtin_amdgcn_mfma_f32_16x16x32_bf16(a0.s, b0.s, acc[nf], 0, 0, 0);
    acc[nf] = __builtin_amdgcn_mfma_f32_16x16x32_bf16(a1.s, b1v.s, acc[nf], 0, 0, 0);
  }

  // epilogue: oc = wave*16 + quad*4 + reg; px col = l16
  float4 bb = *(const float4*)(b1 + wave * 16 + quad * 4);
  unsigned short* obase = act1p + (size_t)bt * 166400u;
#pragma unroll
  for (int nf = 0; nf < 4; nf++) {
    int p = nb * 64 + nf * 16 + l16;
    int oh = p / 48, ow = p % 48;
    unsigned short* dst = obase + (oh + 1) * 52 + (ow + 1);
#pragma unroll
    for (int reg = 0; reg < 4; reg++) {
      int oc = wave * 16 + quad * 4 + reg;
      float bias = (reg == 0) ? bb.x : (reg == 1) ? bb.y : (reg == 2) ? bb.z : bb.w;
      dst[oc * 2600] = f2bf(fmaxf(acc[nf][reg] + bias, 0.f));
    }
  }
}

// ============ conv2 (MFMA): act1p -> relu -> act2p [26][26][128] channel-last ============
__global__ __launch_bounds__(256) void conv2_kernel(
    const unsigned short* __restrict__ act1p, const unsigned short* __restrict__ w2a,
    const float* __restrict__ b2, unsigned short* __restrict__ act2p) {
  __shared__ unsigned short Blds[2][64 * 40];
  int tid = threadIdx.x;
  int nb = blockIdx.x, bt = blockIdx.y;
  int wave = tid >> 6, lane = tid & 63, quad = lane >> 4, l16 = lane & 15;
  int nB = tid & 63, g = tid >> 6;
  int icl = g >> 1, khp = g & 1;
  int pB = nb * 64 + nB;
  int ohB = pB / 24, owB = pB % 24;
  const unsigned short* gbase =
      act1p + (size_t)bt * 166400u + icl * 2600 + (2 * ohB + khp * 2) * 52 + 2 * owB;
  const unsigned short* aptr0 = w2a + (wave * 32 + l16) * 1024 + quad * 8;
  const unsigned short* aptr1 = aptr0 + 16 * 1024;

  floatx4 acc[2][4];
#pragma unroll
  for (int i = 0; i < 2; i++)
#pragma unroll
    for (int j = 0; j < 4; j++) acc[i][j] = (floatx4){0.f, 0.f, 0.f, 0.f};

  uint4 bv;
  bv.x = *(const unsigned int*)(gbase);
  bv.y = *(const unsigned int*)(gbase + 2);
  bv.z = *(const unsigned int*)(gbase + 52);
  bv.w = *(const unsigned int*)(gbase + 54);
  *(uint4*)(&Blds[0][nB * 40 + g * 8]) = bv;
  UV a_cur0, a_cur1, a_nxt0, a_nxt1;
  a_cur0.u = *(const uint4*)(aptr0);
  a_cur1.u = *(const uint4*)(aptr1);
  __syncthreads();

  for (int kk = 0; kk < 32; kk++) {
    int cur = kk & 1;
    UV bfrag[4];
#pragma unroll
    for (int nf = 0; nf < 4; nf++)
      bfrag[nf].u = *(const uint4*)(&Blds[cur][(nf * 16 + l16) * 40 + quad * 8]);
    uint4 bnv;
    if (kk < 31) {
      const unsigned short* p = gbase + (kk + 1) * 5200;  // 2 ic per K-step
      bnv.x = *(const unsigned int*)(p);
      bnv.y = *(const unsigned int*)(p + 2);
      bnv.z = *(const unsigned int*)(p + 52);
      bnv.w = *(const unsigned int*)(p + 54);
      a_nxt0.u = *(const uint4*)(aptr0 + (kk + 1) * 32);
      a_nxt1.u = *(const uint4*)(aptr1 + (kk + 1) * 32);
    }
#pragma unroll
    for (int nf = 0; nf < 4; nf++) {
      acc[0][nf] = __builtin_amdgcn_mfma_f32_16x16x32_bf16(a_cur0.s, bfrag[nf].s, acc[0][nf], 0, 0, 0);
      acc[1][nf] = __builtin_amdgcn_mfma_f32_16x16x32_bf16(a_cur1.s, bfrag[nf].s, acc[1][nf], 0, 0, 0);
    }
    if (kk < 31) *(uint4*)(&Blds[1 - cur][nB * 40 + g * 8]) = bnv;
    __syncthreads();
    a_cur0 = a_nxt0; a_cur1 = a_nxt1;
  }

  unsigned short* obase = act2p + (size_t)bt * 86528u;
#pragma unroll
  for (int mf = 0; mf < 2; mf++) {
    int oc0 = wave * 32 + mf * 16 + quad * 4;
    float4 bb = *(const float4*)(b2 + oc0);
#pragma unroll
    for (int nf = 0; nf < 4; nf++) {
      int p = nb * 64 + nf * 16 + l16;
      int oh = p / 24, ow = p % 24;
      float v0 = fmaxf(acc[mf][nf][0] + bb.x, 0.f);
      float v1 = fmaxf(acc[mf][nf][1] + bb.y, 0.f);
      float v2 = fmaxf(acc[mf][nf][2] + bb.z, 0.f);
      float v3 = fmaxf(acc[mf][nf][3] + bb.w, 0.f);
      uint2 o;
      o.x = (unsigned)f2bf(v0) | ((unsigned)f2bf(v1) << 16);
      o.y = (unsigned)f2bf(v2) | ((unsigned)f2bf(v3) << 16);
      *(uint2*)(obase + ((oh + 1) * 26 + (ow + 1)) * 128 + oc0) = o;
    }
  }
}

// ============ deconv3 (MFMA): act2p -> relu -> act3 [BT][64][48][48] ============
__global__ __launch_bounds__(256) void deconv3_kernel(
    const unsigned short* __restrict__ act2p, const unsigned short* __restrict__ w3a,
    const float* __restrict__ b3, unsigned short* __restrict__ act3) {
  __shared__ unsigned short Blds[2][2][64 * 40];
  int tid = threadIdx.x;
  int nb = blockIdx.x, r = blockIdx.y, bt = blockIdx.z;
  int wave = tid >> 6, lane = tid & 63, quad = lane >> 4, l16 = lane & 15;
  int nB = tid & 63, g = tid >> 6;
  int pB = nb * 64 + nB;
  int iB = pB / 24, jB = pB % 24;
  const unsigned short* a2 = act2p + (size_t)bt * 86528u;
  const unsigned short* A0 = w3a + (r * 2) * 32768 + (wave * 16 + l16) * 512 + quad * 8;
  const unsigned short* A1 = A0 + 32768;

  floatx4 acc[2][4];
#pragma unroll
  for (int i = 0; i < 2; i++)
#pragma unroll
    for (int j = 0; j < 4; j++) acc[i][j] = (floatx4){0.f, 0.f, 0.f, 0.f};

  {
    int row = iB + r + 1;
    const unsigned short* p = a2 + (row * 26 + jB + 1) * 128 + g * 8;
    uint4 b0 = *(const uint4*)(p);
    uint4 b1 = *(const uint4*)(p + 128);
    *(uint4*)(&Blds[0][0][nB * 40 + g * 8]) = b0;
    *(uint4*)(&Blds[0][1][nB * 40 + g * 8]) = b1;
  }
  UV a_cur0, a_cur1, a_nxt0, a_nxt1;
  a_cur0.u = *(const uint4*)(A0);
  a_cur1.u = *(const uint4*)(A1);
  __syncthreads();

  for (int kk = 0; kk < 16; kk++) {
    int cur = kk & 1;
    UV bfrag[2][4];
#pragma unroll
    for (int s = 0; s < 2; s++)
#pragma unroll
      for (int nf = 0; nf < 4; nf++)
        bfrag[s][nf].u = *(const uint4*)(&Blds[cur][s][(nf * 16 + l16) * 40 + quad * 8]);
    uint4 bn0, bn1;
    if (kk < 15) {
      int kn = kk + 1;
      int ab = kn >> 2, ic0 = (kn & 3) * 32;
      int a = ab >> 1, b = ab & 1;
      int row = iB + r - a + 1;
      const unsigned short* p = a2 + (row * 26 + jB + 1 - b) * 128 + ic0 + g * 8;
      bn0 = *(const uint4*)(p);
      bn1 = *(const uint4*)(p + 128);
      a_nxt0.u = *(const uint4*)(A0 + kn * 32);
      a_nxt1.u = *(const uint4*)(A1 + kn * 32);
    }
#pragma unroll
    for (int nf = 0; nf < 4; nf++) {
      acc[0][nf] = __builtin_amdgcn_mfma_f32_16x16x32_bf16(a_cur0.s, bfrag[0][nf].s, acc[0][nf], 0, 0, 0);
      acc[1][nf] = __builtin_amdgcn_mfma_f32_16x16x32_bf16(a_cur1.s, bfrag[1][nf].s, acc[1][nf], 0, 0, 0);
    }
    if (kk < 15) {
      *(uint4*)(&Blds[1 - cur][0][nB * 40 + g * 8]) = bn0;
      *(uint4*)(&Blds[1 - cur][1][nB * 40 + g * 8]) = bn1;
    }
    __syncthreads();
    a_cur0 = a_nxt0; a_cur1 = a_nxt1;
  }

  float4 bb = *(const float4*)(b3 + wave * 16 + quad * 4);
#pragma unroll
  for (int nf = 0; nf < 4; nf++) {
    int n = nb * 64 + nf * 16 + l16;
    int i = n / 24, j = n % 24;
    int oh = 2 * i + r;
#pragma unroll
    for (int reg = 0; reg < 4; reg++) {
      int oc = wave * 16 + quad * 4 + reg;
      float bias = (reg == 0) ? bb.x : (reg == 1) ? bb.y : (reg == 2) ? bb.z : bb.w;
      float v0 = fmaxf(acc[0][nf][reg] + bias, 0.f);
      float v1 = fmaxf(acc[1][nf][reg] + bias, 0.f);
      unsigned int o = (unsigned)f2bf(v0) | ((unsigned)f2bf(v1) << 16);
      *(unsigned int*)(act3 + ((size_t)(bt * 64 + oc)) * 2304u + oh * 48 + 2 * j) = o;
    }
  }
}

// ============ deconv4 + tanh (LDS-staged): act3 -> out fp32 [BT,3,96,96] ============
__global__ __launch_bounds__(256, 2) void deconv4_kernel(
    const unsigned short* __restrict__ act3, const float* __restrict__ w4,
    const float* __restrict__ b4, float* __restrict__ out) {
  __shared__ uint4 s4[2048];  // 32768 B: [0,18432) act chunk, pad zeros at 18432+icl*4608
  char* lds = (char*)s4;
  int tid = threadIdx.x;
  int r = blockIdx.x, bt = blockIdx.y;

  if (tid < 4) *(unsigned short*)(lds + 18432 + tid * 4608) = 0;

  int base[9][6];
#pragma unroll
  for (int it = 0; it < 9; it++) {
    int px = it * 256 + tid;
    int i = px / 48, j = px % 48;
    int ih0 = i + r;
    int ih1 = i + r - 1;
    bool r0 = (ih0 >= 0) && (ih0 < 48);
    bool r1 = (ih1 >= 0) && (ih1 < 48);
    bool c0 = (j - 1) >= 0;
    bool c2 = (j + 1) < 48;
#pragma unroll
    for (int c = 0; c < 3; c++) {
      int iw = j - 1 + c;
      bool cok = (c == 0) ? c0 : ((c == 2) ? c2 : true);
      base[it][c]     = (r0 && cok) ? (ih0 * 48 + iw) * 2 : 18432;
      base[it][3 + c] = (r1 && cok) ? (ih1 * 48 + iw) * 2 : 18432;
    }
  }

  float acc[9][2][3];
#pragma unroll
  for (int it = 0; it < 9; it++)
#pragma unroll
    for (int s = 0; s < 2; s++)
#pragma unroll
      for (int oc = 0; oc < 3; oc++) acc[it][s][oc] = 0.f;

  const uint4* gsrc = (const uint4*)((const char*)act3 + (size_t)bt * 294912u);
  uint4 pre[5];
#pragma unroll
  for (int v = 0; v < 4; v++) pre[v] = gsrc[v * 256 + tid];
  pre[4] = (tid < 128) ? gsrc[1024 + tid] : (uint4){0, 0, 0, 0};

  int kh0 = 1 - r, kh1 = 3 - r;

  for (int ch = 0; ch < 16; ch++) {
    __syncthreads();
#pragma unroll
    for (int v = 0; v < 4; v++) s4[v * 256 + tid] = pre[v];
    if (tid < 128) s4[1024 + tid] = pre[4];
    __syncthreads();
    if (ch < 15) {
      const uint4* gq = gsrc + (ch + 1) * 1152;
#pragma unroll
      for (int v = 0; v < 4; v++) pre[v] = gq[v * 256 + tid];
      if (tid < 128) pre[4] = gq[1024 + tid];
    }
#pragma unroll
    for (int icl = 0; icl < 4; icl++) {
      const float* wic = w4 + (ch * 4 + icl) * 48;
      float W0[3][4], W1[3][4];
#pragma unroll
      for (int oc = 0; oc < 3; oc++)
#pragma unroll
        for (int kw = 0; kw < 4; kw++) {
          W0[oc][kw] = wic[oc * 16 + kh0 * 4 + kw];
          W1[oc][kw] = wic[oc * 16 + kh1 * 4 + kw];
        }
      const char* lb = lds + icl * 4608;
#pragma unroll
      for (int it = 0; it < 9; it++) {
        float v0c0 = bf2f(*(const unsigned short*)(lb + base[it][0]));
        float v0c1 = bf2f(*(const unsigned short*)(lb + base[it][1]));
        float v0c2 = bf2f(*(const unsigned short*)(lb + base[it][2]));
        float v1c0 = bf2f(*(const unsigned short*)(lb + base[it][3]));
        float v1c1 = bf2f(*(const unsigned short*)(lb + base[it][4]));
        float v1c2 = bf2f(*(const unsigned short*)(lb + base[it][5]));
#pragma unroll
        for (int oc = 0; oc < 3; oc++) {
          acc[it][0][oc] += v0c1 * W0[oc][1] + v0c0 * W0[oc][3]
                          + v1c1 * W1[oc][1] + v1c0 * W1[oc][3];
          acc[it][1][oc] += v0c2 * W0[oc][0] + v0c1 * W0[oc][2]
                          + v1c2 * W1[oc][0] + v1c1 * W1[oc][2];
        }
      }
    }
  }

  float bias[3] = { b4[0], b4[1], b4[2] };
#pragma unroll
  for (int it = 0; it < 9; it++) {
    int px = it * 256 + tid;
    int i = px / 48, j = px % 48;
    int oh = 2 * i + r;
#pragma unroll
    for (int oc = 0; oc < 3; oc++) {
      float2 o;
      o.x = ftanh(acc[it][0][oc] + bias[oc]);
      o.y = ftanh(acc[it][1][oc] + bias[oc]);
      *(float2*)(out + (size_t)bt * 27648 + oc * 9216 + oh * 96 + 2 * j) = o;
    }
  }
}

extern "C" void kernel_launch(void* const* d_in, const int* in_sizes, int n_in,
                              void* d_out, int out_size, void* d_ws, size_t ws_size,
                              hipStream_t stream) {
  const float* ident = (const float*)d_in[0];
  const float* lm = (const float*)d_in[1];
  const float* w1 = (const float*)d_in[2];
  const float* b1 = (const float*)d_in[3];
  const float* w2 = (const float*)d_in[4];
  const float* b2 = (const float*)d_in[5];
  const float* w3 = (const float*)d_in[6];
  const float* b3 = (const float*)d_in[7];
  const float* w4 = (const float*)d_in[8];
  const float* b4 = (const float*)d_in[9];
  float* out = (float*)d_out;
  char* ws = (char*)d_ws;
  unsigned short* identp = (unsigned short*)(ws + IDENTP_OFF);
  unsigned short* hmp = (unsigned short*)(ws + HMP_OFF);
  unsigned short* act1p = (unsigned short*)(ws + ACT1P_OFF);
  unsigned short* act2p = (unsigned short*)(ws + ACT2P_OFF);
  unsigned short* act3 = (unsigned short*)(ws + ACT3_OFF);
  unsigned short* w2a = (unsigned short*)(ws + W2A_OFF);
  unsigned short* w3a = (unsigned short*)(ws + W3A_OFF);
  unsigned short* w1b = (unsigned short*)(ws + W1B_OFF);

  prep_kernel<<<dim3(921), 256, 0, stream>>>(lm, ident, w1, w2, w3, identp, hmp,
                                             w1b, w2a, w3a, act1p, act2p);
  conv1_kernel<<<dim3(36, 256), 256, 0, stream>>>(identp, hmp, w1b, b1, act1p);
  conv2_kernel<<<dim3(9, 256), 256, 0, stream>>>(act1p, w2a, b2, act2p);
  deconv3_kernel<<<dim3(9, 2, 256), 256, 0, stream>>>(act2p, w3a, b3, act3);
  deconv4_kernel<<<dim3(2, 256), 256, 0, stream>>>(act3, w4, b4, out);
}